// Round 4
// baseline (38.209 us; speedup 1.0000x reference)
//
#include <hip/hip_runtime.h>

// Fused 2-level 3D Haar DWT (Patcher3D, patch_size=4).
// Input  x  : [4, 3, 33, 256, 256] f32  (frame 0 logically repeated 4x on T)
// Output out: [4, 192, 9, 64, 64]  f32
// out[b, band2*24 + band1*3 + c, t2, h2, w2] =
//   (1/64) * sum_{u,v,w in [0,4)} Wt[u]*Wh[v]*Ww[w] * xin[b,c,4t2+u,4h2+v,4w2+w]
// R4 change: async global->LDS staging (global_load_lds, 16B) to decouple
// memory-level parallelism from VGPR budget. Each 128-thread block stages its
// full 32KB input tile (32 rows x 1KB) asynchronously, then computes from LDS.
// 5 blocks/CU x 32KB = 160KB in flight per CU vs ~2.6KB before.

#define HW_IN   65536      // 256*256
#define THW_OUT 36864      // 9*64*64

__global__ __launch_bounds__(128) void patcher3d_haar2(
    const float* __restrict__ x, float* __restrict__ out)
{
    __shared__ __align__(16) float lds[4 * 8 * 256];   // 32 KB: [u][row][256]

    const int lane = threadIdx.x & 63;
    const int wave = threadIdx.x >> 6;

    int gid = blockIdx.x;
    const int h2g = gid & 31;  gid >>= 5;   // 32 groups of 2 h2 rows
    const int t2  = gid % 9;   gid /= 9;
    const int c   = gid % 3;
    const int b   = gid / 3;

    const float* __restrict__ xp = x + (size_t)(b * 3 + c) * 33 * HW_IN;
    const int hbase = h2g * 8;              // first input H row of this block

    // ---- async stage: 32 rows of 1KB; wave w issues rows k = w*16 .. w*16+15
#pragma unroll
    for (int i = 0; i < 16; ++i) {
        const int k   = wave * 16 + i;
        const int u   = k >> 3;
        const int row = k & 7;
        int tf = 4 * t2 + u - 3;
        tf = tf < 0 ? 0 : tf;               // repeated first frame
        const float* src = xp + (size_t)tf * HW_IN
                              + (size_t)(hbase + row) * 256 + lane * 4;
        float* dst = &lds[k * 256];         // HW adds lane*16B on LDS side
        __builtin_amdgcn_global_load_lds(
            (const __attribute__((address_space(1))) void*)src,
            (__attribute__((address_space(3))) void*)dst, 16, 0, 0);
    }
    __syncthreads();   // drains vmcnt before any wave reads LDS

    // ---- compute from LDS
    const int h2 = h2g * 2 + wave;          // [0,64)
    const int w2 = lane;                    // [0,64)

    float tacc[4][4][4];                    // [pt][ph][pw]
#pragma unroll
    for (int i = 0; i < 4; ++i)
#pragma unroll
        for (int j = 0; j < 4; ++j)
#pragma unroll
            for (int k = 0; k < 4; ++k) tacc[i][j][k] = 0.0f;

#pragma unroll
    for (int u = 0; u < 4; ++u) {
        float hacc[4][4];
#pragma unroll
        for (int j = 0; j < 4; ++j)
#pragma unroll
            for (int k = 0; k < 4; ++k) hacc[j][k] = 0.0f;

#pragma unroll
        for (int v = 0; v < 4; ++v) {
            const int row = wave * 4 + v;   // local row within the 8 staged
            const float4 r = *reinterpret_cast<const float4*>(
                &lds[(u * 8 + row) * 256 + w2 * 4]);

            // W-axis 4-point WHT (8 adds)
            const float sA = r.x + r.y, dA = r.x - r.y;
            const float sB = r.z + r.w, dB = r.z - r.w;
            float sw[4];
            sw[0] = sA + sB;   // (L2,L1)
            sw[1] = dA + dB;   // (L2,H1)
            sw[2] = sA - sB;   // (H2,L1)
            sw[3] = dA - dB;   // (H2,H1)

            // H-axis accumulate with compile-time +-1 weights
#pragma unroll
            for (int ph = 0; ph < 4; ++ph) {
                const bool neg = ((((ph >> 1) & (v >> 1)) ^ ((ph & 1) & (v & 1))) != 0);
                if (neg) {
#pragma unroll
                    for (int pw = 0; pw < 4; ++pw) hacc[ph][pw] -= sw[pw];
                } else {
#pragma unroll
                    for (int pw = 0; pw < 4; ++pw) hacc[ph][pw] += sw[pw];
                }
            }
        }

        // T-axis accumulate
#pragma unroll
        for (int pt = 0; pt < 4; ++pt) {
            const bool neg = ((((pt >> 1) & (u >> 1)) ^ ((pt & 1) & (u & 1))) != 0);
            if (neg) {
#pragma unroll
                for (int j = 0; j < 4; ++j)
#pragma unroll
                    for (int k = 0; k < 4; ++k) tacc[pt][j][k] -= hacc[j][k];
            } else {
#pragma unroll
                for (int j = 0; j < 4; ++j)
#pragma unroll
                    for (int k = 0; k < 4; ++k) tacc[pt][j][k] += hacc[j][k];
            }
        }
    }

    // ---- store: out[b][ch][t2][h2][w2], ch = band2*24 + band1*3 + c
    const float scale = 1.0f / 64.0f;
    float* __restrict__ ob = out + (size_t)b * 192 * THW_OUT
                                 + (size_t)t2 * (64 * 64) + h2 * 64 + w2;
#pragma unroll
    for (int pt = 0; pt < 4; ++pt)
#pragma unroll
        for (int ph = 0; ph < 4; ++ph)
#pragma unroll
            for (int pw = 0; pw < 4; ++pw) {
                const int band2 = ((pt >> 1) << 2) | ((ph >> 1) << 1) | (pw >> 1);
                const int band1 = ((pt & 1) << 2) | ((ph & 1) << 1) | (pw & 1);
                const int ch = band2 * 24 + band1 * 3 + c;
                ob[(size_t)ch * THW_OUT] = tacc[pt][ph][pw] * scale;
            }
}

extern "C" void kernel_launch(void* const* d_in, const int* in_sizes, int n_in,
                              void* d_out, int out_size, void* d_ws, size_t ws_size,
                              hipStream_t stream)
{
    const float* x = (const float*)d_in[0];
    float* out = (float*)d_out;
    // grid: 4 (b) * 3 (c) * 9 (t2) * 32 (h2 pairs) = 3456 blocks of 128 threads
    dim3 grid(3456), block(128);
    hipLaunchKernelGGL(patcher3d_haar2, grid, block, 0, stream, x, out);
}